// Round 7
// baseline (167.474 us; speedup 1.0000x reference)
//
#include <hip/hip_runtime.h>
#include <hip/hip_bf16.h>

#define NROW 1600
#define NEG  3200
#define ROWS_FLAT 25600
#define NSPLIT 25        // 25 x 128 = 3200 j's
#define TPB 4            // tiles (of 2 i's x 16 t) per k_proj block

using bf16x8 = __attribute__((ext_vector_type(8))) short;
using f32x4  = __attribute__((ext_vector_type(4))) float;

__device__ __forceinline__ float bf2f(unsigned v) { return __uint_as_float(v << 16); }
__device__ __forceinline__ ushort f2bf(float f) {
  __hip_bfloat16 h = __float2bfloat16(f);
  return *(ushort*)&h;
}
__device__ __forceinline__ float load1(const ushort* p, size_t idx, int f32) {
  return f32 ? ((const float*)p)[idx] : bf2f(p[idx]);
}
// wave-level dtype sniff: 1 = fp32, 0 = bf16. Reads ushorts 0..127 of buffer.
__device__ __forceinline__ int sniff_f32(const ushort* p, int lane) {
  unsigned e = ((unsigned)p[2*lane] >> 7) & 0xffu;
  unsigned long long b = __ballot(e >= 100u && e <= 140u);
  return (__popcll(b) >= 40) ? 0 : 1;
}
// two float4 granules -> bf16x8 (RNE, same as before)
__device__ __forceinline__ bf16x8 cvt8b(const float* a, const float* b) {
  float4 fa = *(const float4*)a;
  float4 fb = *(const float4*)b;
  bf16x8 r;
  r[0]=(short)f2bf(fa.x); r[1]=(short)f2bf(fa.y); r[2]=(short)f2bf(fa.z); r[3]=(short)f2bf(fa.w);
  r[4]=(short)f2bf(fb.x); r[5]=(short)f2bf(fb.y); r[6]=(short)f2bf(fb.z); r[7]=(short)f2bf(fb.w);
  return r;
}

// ---------------- K0: Wtf = fragment-major bf16(W^T) + zero accumulators ----------
// Wtf layout: for fragment tile (n16 = n>>4, kb = k>>5), lane l = q*16+m holds
// elements k = kb*32+q*8+e, n = n16*16+m at Wtf[((n16*8+kb)*64 + l)*8 + e]
// -> k_proj's b-fragment load is one contiguous 1KB wave-load.
__global__ __launch_bounds__(256) void k_prep(const ushort* __restrict__ W,
    ushort* __restrict__ Wtf, int* __restrict__ zbase) {
  if (blockIdx.x == 0 && threadIdx.x < 21) zbase[threadIdx.x] = 0;  // wsum[4]+cnt[16]+done[1]
  int fW = sniff_f32(W, threadIdx.x & 63);
  int n = blockIdx.x, k = threadIdx.x;
  int n16 = n >> 4, m = n & 15, kb = k >> 5, q = (k >> 3) & 3, e = k & 7;
  Wtf[(size_t)(n16*8 + kb)*512 + q*128 + m*8 + e] =
      f2bf(load1(W, (size_t)k * 256 + n, fW));
}

// ---------------- K1: persistent 4-tile MFMA projection + L2 norm + FUSED bridge ---
// 400 blocks x 4 tiles (2 i's x 16 t each). Double-buffered staging: tile g+1's
// global_load_lds is ISSUED before tile g's k-loop, and drained by the norm
// barrier ~2k cycles later -> staging latency hidden under compute (cross-tile
// pipeline). Epilogue c-buf overlays the CURRENT tile's A-buffer (never the
// prefetch target). Pb written t-major; bridge only for blocks < 200.
__global__ __launch_bounds__(256) void k_proj(const ushort* __restrict__ fe0,
    const ushort* __restrict__ fe1, const ushort* __restrict__ Wtf,
    const ushort* __restrict__ bias, const int* __restrict__ bridge,
    ushort* __restrict__ Pb, ushort* __restrict__ Ab, float* __restrict__ prm,
    float* __restrict__ numer, int* __restrict__ cnt, int* __restrict__ lst,
    float* __restrict__ wsum) {
  __shared__ float sbuf[2][32*256];    // 64 KB: double-buffered A staging
  __shared__ float s_ss[4][32];
  __shared__ float s_bb[4][2][3];      // [wave][ih][xx,aa,sc]
  __shared__ int   s_brg[2][3];
  const int tid = threadIdx.x;
  const int w = tid >> 6, lane = tid & 63, q = lane >> 4, m = lane & 15;
  const int hasB = (blockIdx.x < 200);   // all 4 tiles of a block on one side
  const int s1 = !hasB;
  const ushort* srcp = s1 ? fe1 : fe0;
  const int fSrc = sniff_f32(srcp, lane);
  const int fB   = sniff_f32(bias, lane);
  float bb[4];
  #pragma unroll
  for (int nt = 0; nt < 4; nt++) bb[nt] = load1(bias, w*64 + nt*16 + m, fB);
  const ushort* wfb = Wtf + (size_t)(w*4)*4096 + lane*8;  // + nt*4096 + k*512
  const int sw = (m & 7) << 3;         // bf16 element swizzle (granule ^ (m&7))

  // stage tile g's 32 rows into sbuf[b]; per-lane GLOBAL addr carries the (i,t)
  // gather + bank swizzle; LDS dest is wave-uniform base + lane*16B (linear).
  auto STAGE = [&](int g, int b) {
    int I0g = blockIdx.x*(2*TPB) + g*2;
    int ii = I0g - s1*NROW + (w >> 1);          // flat i index on this side
    int bq = ii / 100, qq = ii - bq*100;
    size_t ub = (size_t)(bq*1600 + qq) * 256;   // elements; + t*100*256
    if (fSrc) {
      const float* fp = (const float*)srcp;
      #pragma unroll
      for (int i2 = 0; i2 < 8; i2++) {          // one 1KB row per issue
        int r = w*8 + i2;                       // tile row; r&7 = i2
        int t = r & 15;
        int gg = lane ^ i2;                     // 16B granule swizzle
        const float* gp = fp + ub + (size_t)t*25600 + gg*4;
        __builtin_amdgcn_global_load_lds(
          (const __attribute__((address_space(1))) unsigned int*)gp,
          (__attribute__((address_space(3))) unsigned int*)&sbuf[b][r*256], 16, 0, 0);
      }
    } else {
      ushort* xb = (ushort*)&sbuf[b][0];
      #pragma unroll
      for (int i2 = 0; i2 < 4; i2++) {          // two 512B rows per issue
        int c = w*4 + i2;
        int r = 2*c + (lane >> 5);              // per-lane row
        int t = r & 15;
        int kc = (lane & 31) ^ (r & 7);
        const ushort* gp = srcp + ub + (size_t)t*25600 + kc*8;
        __builtin_amdgcn_global_load_lds(
          (const __attribute__((address_space(1))) unsigned int*)gp,
          (__attribute__((address_space(3))) unsigned int*)&xb[c*512], 16, 0, 0);
      }
    }
  };

  STAGE(0, 0);
  for (int g = 0; g < TPB; g++) {
    const int b = g & 1;
    const int I0g = blockIdx.x*(2*TPB) + g*2;
    if (g + 1 < TPB) STAGE(g + 1, b ^ 1);   // issue next tile's loads NOW
    if (g == 0) __syncthreads();            // prologue only: tile 0 staged
    const float*  xf = &sbuf[b][0];
    const ushort* xb = (const ushort*)xf;
    ushort*       cb = (ushort*)&sbuf[b][0];  // epilogue overlay of CURRENT buf
    // acc[mt][nt]: rows mt*16+(4q+reg), cols w*64+nt*16+m ; init with bias
    f32x4 acc[2][4];
    #pragma unroll
    for (int nt = 0; nt < 4; nt++) {
      f32x4 v = {bb[nt], bb[nt], bb[nt], bb[nt]};
      acc[0][nt] = v; acc[1][nt] = v;
    }
    // software-pipelined k-loop: prefetch k+1 fragments before k's MFMAs
    bf16x8 a_cur[2], b_cur[4];
    if (fSrc) {
      int g0 = (q*2) ^ (m&7), g1 = (q*2 + 1) ^ (m&7);
      #pragma unroll
      for (int mt = 0; mt < 2; mt++)
        a_cur[mt] = cvt8b(&xf[(mt*16+m)*256 + g0*4], &xf[(mt*16+m)*256 + g1*4]);
    } else {
      #pragma unroll
      for (int mt = 0; mt < 2; mt++)
        a_cur[mt] = *(const bf16x8*)&xb[(mt*16 + m)*256 + ((q*8) ^ sw)];
    }
    #pragma unroll
    for (int nt = 0; nt < 4; nt++)
      b_cur[nt] = *(const bf16x8*)(wfb + (size_t)nt*4096);
    #pragma unroll
    for (int k = 0; k < 8; k++) {
      bf16x8 a_nxt[2], b_nxt[4];
      if (k < 7) {
        #pragma unroll
        for (int nt = 0; nt < 4; nt++)
          b_nxt[nt] = *(const bf16x8*)(wfb + (size_t)nt*4096 + (k+1)*512);
        if (fSrc) {
          int g0 = ((k+1)*8 + q*2) ^ (m&7), g1 = ((k+1)*8 + q*2 + 1) ^ (m&7);
          #pragma unroll
          for (int mt = 0; mt < 2; mt++)
            a_nxt[mt] = cvt8b(&xf[(mt*16+m)*256 + g0*4], &xf[(mt*16+m)*256 + g1*4]);
        } else {
          int pk = ((k+1)*32 + q*8) ^ sw;
          #pragma unroll
          for (int mt = 0; mt < 2; mt++)
            a_nxt[mt] = *(const bf16x8*)&xb[(mt*16 + m)*256 + pk];
        }
      }
      #pragma unroll
      for (int nt = 0; nt < 4; nt++)
        #pragma unroll
        for (int mt = 0; mt < 2; mt++)
          acc[mt][nt] = __builtin_amdgcn_mfma_f32_16x16x32_bf16(a_cur[mt], b_cur[nt], acc[mt][nt], 0, 0, 0);
      if (k < 7) {
        a_cur[0] = a_nxt[0]; a_cur[1] = a_nxt[1];
        #pragma unroll
        for (int x = 0; x < 4; x++) b_cur[x] = b_nxt[x];
      }
    }
    // cross-wave row-norm: partial ss per (mt,reg) over this wave's 64 cols
    float ssp[2][4];
    #pragma unroll
    for (int mt = 0; mt < 2; mt++)
      #pragma unroll
      for (int reg = 0; reg < 4; reg++) {
        float s = 0.f;
        #pragma unroll
        for (int nt = 0; nt < 4; nt++) { float v = acc[mt][nt][reg]; s += v*v; }
        ssp[mt][reg] = s;
      }
    #pragma unroll
    for (int mk = 1; mk < 16; mk <<= 1)
      #pragma unroll
      for (int mt = 0; mt < 2; mt++)
        #pragma unroll
        for (int reg = 0; reg < 4; reg++) ssp[mt][reg] += __shfl_xor(ssp[mt][reg], mk, 64);
    if (m == 0)
      #pragma unroll
      for (int mt = 0; mt < 2; mt++)
        #pragma unroll
        for (int reg = 0; reg < 4; reg++) s_ss[w][mt*16 + 4*q + reg] = ssp[mt][reg];
    __syncthreads();   // B1: s_ss ready; retires A reads; drains STAGE(g+1)
    if (hasB && tid < 6) s_brg[tid/3][tid%3] = bridge[(I0g + tid/3)*3 + tid%3];
    float inv[2][4];
    #pragma unroll
    for (int mt = 0; mt < 2; mt++)
      #pragma unroll
      for (int reg = 0; reg < 4; reg++) {
        int row = mt*16 + 4*q + reg;
        float s = s_ss[0][row] + s_ss[1][row] + s_ss[2][row] + s_ss[3][row];
        inv[mt][reg] = 1.0f / sqrtf(s);
      }
    // park bf16 into overlay of CURRENT buffer (stride 72)
    #pragma unroll
    for (int mt = 0; mt < 2; mt++)
      #pragma unroll
      for (int reg = 0; reg < 4; reg++) {
        int rl = mt*16 + 4*q + reg;
        #pragma unroll
        for (int nt = 0; nt < 4; nt++)
          cb[w*2304 + rl*72 + nt*16 + m] = f2bf(acc[mt][nt][reg] * inv[mt][reg]);
      }
    __syncthreads();   // B2: c-bufs complete; stores read across waves
    // 32 consecutive lanes write one full 512B (t,I)-row; 2 rows / instruction
    #pragma unroll
    for (int p = 0; p < 4; p++) {
      int row = p*8 + (tid >> 5);            // tile row 0..31
      int ig  = row >> 4, t = row & 15;
      int I   = I0g + ig;
      int ch  = tid & 31;                    // 32 x 16B chunks
      uint4 v = *(uint4*)&cb[(ch >> 3)*2304 + row*72 + (ch & 7)*8];
      *(uint4*)(Pb + ((size_t)t * NEG + I) * 256 + ch*8) = v;
    }
    if (hasB) {
      // fused bridge: per wave, cols w*64+lane of the 2 i's
      #pragma unroll
      for (int ih = 0; ih < 2; ih++) {
        int bh = s_brg[ih][0], bp = s_brg[ih][1], bt = s_brg[ih][2];
        float alpha = ((float)bp - (float)bh) / ((float)bt - (float)bh);
        int rb = ih*16;
        float g0 = bf2f(cb[w*2304 + (rb + bh)*72 + lane]);
        float g1 = bf2f(cb[w*2304 + (rb + bp)*72 + lane]);
        float g2 = bf2f(cb[w*2304 + (rb + bt)*72 + lane]);
        float hd = bf2f(cb[w*2304 + (rb +  0)*72 + lane]);
        float tl = bf2f(cb[w*2304 + (rb + 15)*72 + lane]);
        float a = (1.0f - alpha) * g0 + alpha * g2;
        float x = g1 - a;
        int I = I0g + ih;
        Ab[(size_t)I*256 + w*64 + lane] = f2bf(a);
        float xx = x*x, aa = a*a, sc = hd*tl;
        #pragma unroll
        for (int mk = 1; mk < 64; mk <<= 1) {
          xx += __shfl_xor(xx, mk, 64);
          aa += __shfl_xor(aa, mk, 64);
          sc += __shfl_xor(sc, mk, 64);
        }
        if (lane == 0) { s_bb[w][ih][0] = xx; s_bb[w][ih][1] = aa; s_bb[w][ih][2] = sc; }
      }
    }
    __syncthreads();   // B3: s_bb ready; c-buf reads retired (next STAGE may hit it)
    if (hasB && tid < 2) {
      int I = I0g + tid;
      float XX = s_bb[0][tid][0] + s_bb[1][tid][0] + s_bb[2][tid][0] + s_bb[3][tid][0];
      float AA = s_bb[0][tid][1] + s_bb[1][tid][1] + s_bb[2][tid][1] + s_bb[3][tid][1];
      float SC = s_bb[0][tid][2] + s_bb[1][tid][2] + s_bb[2][tid][2] + s_bb[3][tid][2];
      int bh = s_brg[tid][0], bp = s_brg[tid][1], bt = s_brg[tid][2];
      float alpha = ((float)bp - (float)bh) / ((float)bt - (float)bh);
      float sigma = alpha * ((float)bt - (float)bp);
      float inv2s2 = 1.0f / (2.0f * sigma * sigma);
      prm[I*2+0] = inv2s2;
      prm[I*2+1] = AA;
      numer[I] = expf(-XX * inv2s2);
      float sp = log1pf(expf(0.3f - SC));
      atomicAdd(wsum + 1, sp * (1.0f / 1600.0f));
      int pos = atomicAdd(cnt + bp, 1);
      lst[bp * 1600 + pos] = I;
    }
  }
}

// ---------------- top-5 helpers ----------------
__device__ __forceinline__ void sort5(float* c) {
  #define CE(i,j) { float hi = fmaxf(c[i], c[j]), lo = fminf(c[i], c[j]); c[i]=hi; c[j]=lo; }
  CE(0,1) CE(3,4) CE(2,4) CE(2,3) CE(1,4) CE(0,3) CE(0,2) CE(1,3) CE(1,2)
  #undef CE
}
__device__ __forceinline__ void ins5(float* t, float v) {
  float hi, lo;
  hi = fmaxf(t[0], v); lo = fminf(t[0], v); t[0] = hi; v = lo;
  hi = fmaxf(t[1], v); lo = fminf(t[1], v); t[1] = hi; v = lo;
  hi = fmaxf(t[2], v); lo = fminf(t[2], v); t[2] = hi; v = lo;
  hi = fmaxf(t[3], v); lo = fminf(t[3], v); t[3] = hi; v = lo;
  t[4] = fmaxf(t[4], v);
}

// ---------------- K3: fused dist + per-split top-5 (64 i's/block, pipelined) ----------------
// Pb is t-major: j-rows for one t are contiguous (128 rows = 64 KB per block).
__global__ __launch_bounds__(256) void k_cross(const ushort* __restrict__ Pb,
    const ushort* __restrict__ Ab, const float* __restrict__ prm,
    const int* __restrict__ cnt, const int* __restrict__ lst,
    float* __restrict__ part) {
  int t = blockIdx.z;
  int n_t = min(cnt[t], 1600);
  int i0 = blockIdx.y * 64;
  if (i0 >= n_t) return;
  int j0 = blockIdx.x * 128;
  __shared__ int s_gis[64];
  __shared__ float s_red[4][64][6];
  int tid = threadIdx.x;
  if (tid < 64) {
    int gi = lst[t*1600 + min(i0 + tid, n_t - 1)];
    s_gis[tid] = min(max(gi, 0), NROW - 1);
  }
  __syncthreads();
  const int w = tid >> 6, lane = tid & 63, q = lane >> 4, m = lane & 15;
  const ushort* jp0 = Pb + ((size_t)t * NEG + (j0 + w*32 + m)) * 256 + q*8;
  const ushort* jp1 = jp0 + (size_t)16*256;
  int gi[4];
  const ushort* ip[4];
  #pragma unroll
  for (int it = 0; it < 4; it++) {
    gi[it] = s_gis[it*16 + m];
    ip[it] = Ab + (size_t)gi[it] * 256 + q*8;
  }
  f32x4 acc[2][4];   // [jt][it]
  #pragma unroll
  for (int jt = 0; jt < 2; jt++)
    #pragma unroll
    for (int it = 0; it < 4; it++) { f32x4 z = {0.f,0.f,0.f,0.f}; acc[jt][it] = z; }
  // pipelined: prefetch k+1 while MFMA-ing k
  bf16x8 jc0 = *(const bf16x8*)(jp0);
  bf16x8 jc1 = *(const bf16x8*)(jp1);
  bf16x8 ic[4];
  #pragma unroll
  for (int it = 0; it < 4; it++) ic[it] = *(const bf16x8*)(ip[it]);
  #pragma unroll
  for (int k = 0; k < 8; k++) {
    bf16x8 jn0, jn1, in[4];
    if (k < 7) {
      int o = (k + 1) * 32;
      jn0 = *(const bf16x8*)(jp0 + o);
      jn1 = *(const bf16x8*)(jp1 + o);
      #pragma unroll
      for (int it = 0; it < 4; it++) in[it] = *(const bf16x8*)(ip[it] + o);
    }
    __builtin_amdgcn_s_setprio(1);
    #pragma unroll
    for (int it = 0; it < 4; it++) {
      acc[0][it] = __builtin_amdgcn_mfma_f32_16x16x32_bf16(jc0, ic[it], acc[0][it], 0, 0, 0);
      acc[1][it] = __builtin_amdgcn_mfma_f32_16x16x32_bf16(jc1, ic[it], acc[1][it], 0, 0, 0);
    }
    __builtin_amdgcn_s_setprio(0);
    if (k < 7) { jc0 = jn0; jc1 = jn1;
      #pragma unroll
      for (int it = 0; it < 4; it++) ic[it] = in[it];
    }
  }
  // per-lane top5/self per it-column. D: row(j) = 4q+reg (+jt*16), col(i) = m.
  float top[4][5], selfv[4];
  float pi[4], pa[4];
  #pragma unroll
  for (int it = 0; it < 4; it++) {
    pi[it] = prm[gi[it]*2]; pa[it] = prm[gi[it]*2+1];
    selfv[it] = -1e30f;
    #pragma unroll
    for (int k = 0; k < 5; k++) top[it][k] = -1e30f;
  }
  #pragma unroll
  for (int jt = 0; jt < 2; jt++)
    #pragma unroll
    for (int reg = 0; reg < 4; reg++) {
      int j = j0 + w*32 + jt*16 + 4*q + reg;
      #pragma unroll
      for (int it = 0; it < 4; it++) {
        float d = -(1.0f - 2.0f*acc[jt][it][reg] + pa[it]) * pi[it];
        if (j == gi[it]) selfv[it] = d; else ins5(top[it], d);
      }
    }
  // reduce over q (lane bits 4,5): bitonic 5-merge + self max
  #pragma unroll
  for (int mk = 16; mk <= 32; mk <<= 1) {
    #pragma unroll
    for (int it = 0; it < 4; it++) {
      float o[5], c[5];
      #pragma unroll
      for (int k = 0; k < 5; k++) o[k] = __shfl_xor(top[it][k], mk, 64);
      #pragma unroll
      for (int k = 0; k < 5; k++) c[k] = fmaxf(top[it][k], o[4 - k]);
      sort5(c);
      #pragma unroll
      for (int k = 0; k < 5; k++) top[it][k] = c[k];
      selfv[it] = fmaxf(selfv[it], __shfl_xor(selfv[it], mk, 64));
    }
  }
  if (q == 0) {
    #pragma unroll
    for (int it = 0; it < 4; it++) {
      #pragma unroll
      for (int k = 0; k < 5; k++) s_red[w][it*16 + m][k] = top[it][k];
      s_red[w][it*16 + m][5] = selfv[it];
    }
  }
  __syncthreads();
  if (tid < 64 && i0 + tid < n_t) {
    float T[5], S = s_red[0][tid][5];
    #pragma unroll
    for (int k = 0; k < 5; k++) T[k] = s_red[0][tid][k];
    #pragma unroll
    for (int w2 = 1; w2 < 4; w2++) {
      #pragma unroll
      for (int k = 0; k < 5; k++) ins5(T, s_red[w2][tid][k]);
      S = fmaxf(S, s_red[w2][tid][5]);
    }
    float* pp = part + ((size_t)s_gis[tid]*NSPLIT + blockIdx.x) * 6;
    #pragma unroll
    for (int k = 0; k < 5; k++) pp[k] = T[k];
    pp[5] = S;
  }
}

// ---------------- K4: parallel merge + last-block output write ----------------
__global__ __launch_bounds__(64) void k_merge(const float* __restrict__ part,
    const float* __restrict__ numer, float* __restrict__ wsum, int* __restrict__ done,
    const ushort* __restrict__ fe0, void* __restrict__ out) {
  int i = blockIdx.x * 64 + threadIdx.x;     // 25 blocks x 64 = 1600
  const float* pp = part + (size_t)i * NSPLIT * 6;
  float T[5]; float S = pp[5];
  #pragma unroll
  for (int k = 0; k < 5; k++) T[k] = pp[k];
  #pragma unroll
  for (int s = 1; s < NSPLIT; s++) {
    const float* ps = pp + s*6;
    float v0 = ps[0], v1 = ps[1], v2 = ps[2], v3 = ps[3], v4 = ps[4], v5 = ps[5];
    ins5(T, v0); ins5(T, v1); ins5(T, v2); ins5(T, v3); ins5(T, v4);
    S = fmaxf(S, v5);
  }
  float deno = expf(S);
  #pragma unroll
  for (int k = 0; k < 5; k++) deno += expf(T[k]);
  float local = numer[i] / deno;
  #pragma unroll
  for (int mk = 1; mk < 64; mk <<= 1) local += __shfl_xor(local, mk, 64);
  __shared__ int s_last;
  if (threadIdx.x == 0) {
    atomicAdd(wsum + 0, local * (1.0f / 1600.0f));
    __threadfence();
    s_last = (atomicAdd(done, 1) == 24);
  }
  __syncthreads();
  if (s_last) {
    int f = sniff_f32(fe0, threadIdx.x);
    if (threadIdx.x == 0) {
      __threadfence();
      float brown = __hip_atomic_load(wsum + 0, __ATOMIC_RELAXED, __HIP_MEMORY_SCOPE_AGENT);
      float sp    = __hip_atomic_load(wsum + 1, __ATOMIC_RELAXED, __HIP_MEMORY_SCOPE_AGENT);
      if (f) {
        ((float*)out)[0] = brown;
        ((float*)out)[1] = sp;
      } else {
        ushort* o = (ushort*)out;
        o[0] = f2bf(brown);
        o[1] = f2bf(sp);
      }
    }
  }
}

extern "C" void kernel_launch(void* const* d_in, const int* in_sizes, int n_in,
                              void* d_out, int out_size, void* d_ws, size_t ws_size,
                              hipStream_t stream) {
  const ushort* fe0    = (const ushort*)d_in[0];
  const ushort* fe1    = (const ushort*)d_in[1];
  const ushort* W      = (const ushort*)d_in[2];
  const ushort* bias   = (const ushort*)d_in[3];
  const int*    bridge = (const int*)d_in[4];

  // workspace (~28 MB)
  ushort* Pb    = (ushort*)d_ws;               // 13,107,200 ushorts (t-major)
  ushort* Ab    = Pb + 13107200;               // 409,600
  ushort* Wtf   = Ab + 409600;                 // 65,536
  float*  part  = (float*)(Wtf + 65536);       // 1600*25*6 = 240,000
  float*  prm   = part + 240000;               // 3,200
  float*  numer = prm + 3200;                  // 1,600
  float*  wsum  = numer + 1600;                // 4 floats
  int*    cnt   = (int*)(wsum + 4);            // 16
  int*    done  = cnt + 16;                    // 1
  int*    lst   = done + 1;                    // 25,600

  k_prep  <<<256, 256, 0, stream>>>(W, Wtf, (int*)wsum);
  k_proj  <<<400, 256, 0, stream>>>(fe0, fe1, Wtf, bias, bridge, Pb, Ab, prm, numer, cnt, lst, wsum);
  k_cross <<<dim3(NSPLIT, 7, 16), 256, 0, stream>>>(Pb, Ab, prm, cnt, lst, part);
  k_merge <<<25, 64, 0, stream>>>(part, numer, wsum, done, fe0, d_out);
}

// Round 8
// 160.602 us; speedup vs baseline: 1.0428x; 1.0428x over previous
//
#include <hip/hip_runtime.h>
#include <hip/hip_bf16.h>

#define NROW 1600
#define NEG  3200
#define ROWS_FLAT 25600
#define NSPLIT 25        // 25 x 128 = 3200 j's

using bf16x8 = __attribute__((ext_vector_type(8))) short;
using f32x4  = __attribute__((ext_vector_type(4))) float;

__device__ __forceinline__ float bf2f(unsigned v) { return __uint_as_float(v << 16); }
__device__ __forceinline__ ushort f2bf(float f) {
  __hip_bfloat16 h = __float2bfloat16(f);
  return *(ushort*)&h;
}
__device__ __forceinline__ float load1(const ushort* p, size_t idx, int f32) {
  return f32 ? ((const float*)p)[idx] : bf2f(p[idx]);
}
// wave-level dtype sniff: 1 = fp32, 0 = bf16. Reads ushorts 0..127 of buffer.
__device__ __forceinline__ int sniff_f32(const ushort* p, int lane) {
  unsigned e = ((unsigned)p[2*lane] >> 7) & 0xffu;
  unsigned long long b = __ballot(e >= 100u && e <= 140u);
  return (__popcll(b) >= 40) ? 0 : 1;
}
// two float4 granules -> bf16x8 (RNE, same as before)
__device__ __forceinline__ bf16x8 cvt8b(const float* a, const float* b) {
  float4 fa = *(const float4*)a;
  float4 fb = *(const float4*)b;
  bf16x8 r;
  r[0]=(short)f2bf(fa.x); r[1]=(short)f2bf(fa.y); r[2]=(short)f2bf(fa.z); r[3]=(short)f2bf(fa.w);
  r[4]=(short)f2bf(fb.x); r[5]=(short)f2bf(fb.y); r[6]=(short)f2bf(fb.z); r[7]=(short)f2bf(fb.w);
  return r;
}

// ---------------- K0: Wtf = fragment-major bf16(W^T) + zero accumulators ----------
// Wtf layout: for fragment tile (n16 = n>>4, kb = k>>5), lane l = q*16+m holds
// elements k = kb*32+q*8+e, n = n16*16+m at Wtf[((n16*8+kb)*64 + l)*8 + e]
// -> k_proj's b-fragment load is one contiguous 1KB wave-load.
__global__ __launch_bounds__(256) void k_prep(const ushort* __restrict__ W,
    ushort* __restrict__ Wtf, int* __restrict__ zbase) {
  if (blockIdx.x == 0 && threadIdx.x < 21) zbase[threadIdx.x] = 0;  // wsum[4]+cnt[16]+done[1]
  int fW = sniff_f32(W, threadIdx.x & 63);
  int n = blockIdx.x, k = threadIdx.x;
  int n16 = n >> 4, m = n & 15, kb = k >> 5, q = (k >> 3) & 3, e = k & 7;
  Wtf[(size_t)(n16*8 + kb)*512 + q*128 + m*8 + e] =
      f2bf(load1(W, (size_t)k * 256 + n, fW));
}

// ---------------- K1: direct-staged MFMA projection + L2 norm + FUSED bridge -------
// Block = 2 i's x 16 t = 32 rows (1600 blocks, ~33KB LDS -> 4 blocks/CU).
// global_load_lds: per-lane GLOBAL addr carries the (i,t) gather and the bank
// swizzle (granule ^ (row&7)); LDS side is linear. fp32 staged raw (32KB) and
// converted at fragment read. Pb written I-MAJOR (row = I*16 + t): the block's
// 32 output rows are ONE contiguous 16KB span -> fully coalesced epilogue store
// (this is the single change vs the R6 kernel; t-major scatter suspected as the
// R0->R3 k_proj regression). Bridge epilogue only for blocks < 800.
__global__ __launch_bounds__(256) void k_proj(const ushort* __restrict__ fe0,
    const ushort* __restrict__ fe1, const ushort* __restrict__ Wtf,
    const ushort* __restrict__ bias, const int* __restrict__ bridge,
    ushort* __restrict__ Pb, ushort* __restrict__ Ab, float* __restrict__ prm,
    float* __restrict__ numer, int* __restrict__ cnt, int* __restrict__ lst,
    float* __restrict__ wsum) {
  __shared__ union {
    float  xf[32*256];     // 32 KB fp32 tile: phys granule = logical ^ (r&7)
    ushort x[32*256];      // 16 KB bf16 tile: phys granule = logical ^ (r&7)
    ushort c[4][32*72];    // 18.4 KB epilogue buffer (stride 72)
  } sh;
  __shared__ float s_ss[4][32];
  __shared__ float s_bb[4][2][3];      // [wave][ih][xx,aa,sc]
  __shared__ int   s_brg[2][3];
  const int tid = threadIdx.x;
  const int w = tid >> 6, lane = tid & 63, q = lane >> 4, m = lane & 15;
  const int I0 = blockIdx.x * 2;
  const int hasB = (I0 < NROW);          // bridge only for cur rows
  const int s1 = (I0 >= NROW);           // block never straddles
  const ushort* srcp = s1 ? fe1 : fe0;
  const int fSrc = sniff_f32(srcp, lane);
  const int fB   = sniff_f32(bias, lane);
  if (hasB && tid < 6) s_brg[tid/3][tid%3] = bridge[(I0 + tid/3)*3 + tid%3];
  // stage: wave w owns rows w*8..w*8+7 (ig = w>>1, t = (w&1)*8 + i2)
  {
    int ii = I0 - s1*NROW + (w >> 1);    // flat i index on this side
    int b = ii / 100, qq = ii - b*100;
    const size_t ub = (size_t)(b*1600 + qq) * 256;   // elements; + t*100*256
    if (fSrc) {
      const float* fp = (const float*)srcp;
      #pragma unroll
      for (int i2 = 0; i2 < 8; i2++) {             // one 1KB row per issue
        int r = w*8 + i2;                          // tile row; r&7 = i2
        int t = r & 15;
        int g = lane ^ (i2 & 7);                   // 16B granule swizzle
        const float* gp = fp + ub + (size_t)t*25600 + g*4;
        __builtin_amdgcn_global_load_lds(
          (const __attribute__((address_space(1))) unsigned int*)gp,
          (__attribute__((address_space(3))) unsigned int*)&sh.xf[r*256], 16, 0, 0);
      }
    } else {
      #pragma unroll
      for (int i2 = 0; i2 < 4; i2++) {             // two 512B rows per issue
        int c = w*4 + i2;
        int r  = 2*c + (lane >> 5);                // per-lane row
        int t  = r & 15;
        int kc = (lane & 31) ^ (r & 7);
        const ushort* gp = srcp + ub + (size_t)t*25600 + kc*8;
        __builtin_amdgcn_global_load_lds(
          (const __attribute__((address_space(1))) unsigned int*)gp,
          (__attribute__((address_space(3))) unsigned int*)&sh.x[c*512], 16, 0, 0);
      }
    }
  }
  __syncthreads();
  // acc[mt][nt]: rows mt*16+(4q+reg), cols w*64+nt*16+m ; init with bias
  f32x4 acc[2][4];
  #pragma unroll
  for (int nt = 0; nt < 4; nt++) {
    float bb = load1(bias, w*64 + nt*16 + m, fB);
    f32x4 v = {bb, bb, bb, bb};
    #pragma unroll
    for (int mt = 0; mt < 2; mt++) acc[mt][nt] = v;
  }
  const int sw = (m & 7) << 3;     // bf16 element swizzle (granule ^ (m&7))
  const ushort* wfb = Wtf + (size_t)(w*4)*4096 + lane*8;  // + nt*4096 + k*512
  // software-pipelined k-loop: prefetch k+1 fragments before k's MFMAs
  bf16x8 a_cur[2], b_cur[4];
  if (fSrc) {
    int g0 = (q*2) ^ (m&7), g1 = (q*2 + 1) ^ (m&7);
    #pragma unroll
    for (int mt = 0; mt < 2; mt++)
      a_cur[mt] = cvt8b(&sh.xf[(mt*16+m)*256 + g0*4], &sh.xf[(mt*16+m)*256 + g1*4]);
  } else {
    #pragma unroll
    for (int mt = 0; mt < 2; mt++)
      a_cur[mt] = *(const bf16x8*)&sh.x[(mt*16 + m)*256 + ((q*8) ^ sw)];
  }
  #pragma unroll
  for (int nt = 0; nt < 4; nt++)
    b_cur[nt] = *(const bf16x8*)(wfb + (size_t)nt*4096);
  #pragma unroll
  for (int k = 0; k < 8; k++) {
    bf16x8 a_nxt[2], b_nxt[4];
    if (k < 7) {
      #pragma unroll
      for (int nt = 0; nt < 4; nt++)
        b_nxt[nt] = *(const bf16x8*)(wfb + (size_t)nt*4096 + (k+1)*512);
      if (fSrc) {
        int g0 = ((k+1)*8 + q*2) ^ (m&7), g1 = ((k+1)*8 + q*2 + 1) ^ (m&7);
        #pragma unroll
        for (int mt = 0; mt < 2; mt++)
          a_nxt[mt] = cvt8b(&sh.xf[(mt*16+m)*256 + g0*4], &sh.xf[(mt*16+m)*256 + g1*4]);
      } else {
        int pk = ((k+1)*32 + q*8) ^ sw;
        #pragma unroll
        for (int mt = 0; mt < 2; mt++)
          a_nxt[mt] = *(const bf16x8*)&sh.x[(mt*16 + m)*256 + pk];
      }
    }
    #pragma unroll
    for (int nt = 0; nt < 4; nt++)
      #pragma unroll
      for (int mt = 0; mt < 2; mt++)
        acc[mt][nt] = __builtin_amdgcn_mfma_f32_16x16x32_bf16(a_cur[mt], b_cur[nt], acc[mt][nt], 0, 0, 0);
    if (k < 7) {
      a_cur[0] = a_nxt[0]; a_cur[1] = a_nxt[1];
      #pragma unroll
      for (int x = 0; x < 4; x++) b_cur[x] = b_nxt[x];
    }
  }
  // cross-wave row-norm: partial ss per (mt,reg) over this wave's 64 cols
  float ssp[2][4];
  #pragma unroll
  for (int mt = 0; mt < 2; mt++)
    #pragma unroll
    for (int reg = 0; reg < 4; reg++) {
      float s = 0.f;
      #pragma unroll
      for (int nt = 0; nt < 4; nt++) { float v = acc[mt][nt][reg]; s += v*v; }
      ssp[mt][reg] = s;
    }
  #pragma unroll
  for (int mk = 1; mk < 16; mk <<= 1)
    #pragma unroll
    for (int mt = 0; mt < 2; mt++)
      #pragma unroll
      for (int reg = 0; reg < 4; reg++) ssp[mt][reg] += __shfl_xor(ssp[mt][reg], mk, 64);
  if (m == 0)
    #pragma unroll
    for (int mt = 0; mt < 2; mt++)
      #pragma unroll
      for (int reg = 0; reg < 4; reg++) s_ss[w][mt*16 + 4*q + reg] = ssp[mt][reg];
  __syncthreads();   // also retires A-tile before c-overlay
  float inv[2][4];
  #pragma unroll
  for (int mt = 0; mt < 2; mt++)
    #pragma unroll
    for (int reg = 0; reg < 4; reg++) {
      int row = mt*16 + 4*q + reg;
      float s = s_ss[0][row] + s_ss[1][row] + s_ss[2][row] + s_ss[3][row];
      inv[mt][reg] = 1.0f / sqrtf(s);
    }
  // park bf16 -> ONE contiguous 16KB coalesced Pb store + fused bridge
  #pragma unroll
  for (int mt = 0; mt < 2; mt++)
    #pragma unroll
    for (int reg = 0; reg < 4; reg++) {
      int rl = mt*16 + 4*q + reg;
      #pragma unroll
      for (int nt = 0; nt < 4; nt++)
        sh.c[w][rl*72 + nt*16 + m] = f2bf(acc[mt][nt][reg] * inv[mt][reg]);
    }
  __syncthreads();   // c-bufs complete; stores read across waves
  // i-major store: global flat row = I0*16 + r (r = ig*16 + t), fully contiguous.
  // thread tid writes 4x16B at elements e = tid*32 + j*8 of the 32x256 tile.
  #pragma unroll
  for (int j = 0; j < 4; j++) {
    int e   = tid*32 + j*8;
    int r   = e >> 8, col = e & 255;
    uint4 v = *(uint4*)&sh.c[col >> 6][r*72 + (col & 63)];
    *(uint4*)(Pb + (size_t)I0*4096 + e) = v;
  }
  if (hasB) {
    // fused bridge: per wave, cols w*64+lane of the 2 i's
    #pragma unroll
    for (int ih = 0; ih < 2; ih++) {
      int bh = s_brg[ih][0], bp = s_brg[ih][1], bt = s_brg[ih][2];
      float alpha = ((float)bp - (float)bh) / ((float)bt - (float)bh);
      int rb = ih*16;
      float g0 = bf2f(sh.c[w][(rb + bh)*72 + lane]);
      float g1 = bf2f(sh.c[w][(rb + bp)*72 + lane]);
      float g2 = bf2f(sh.c[w][(rb + bt)*72 + lane]);
      float hd = bf2f(sh.c[w][(rb +  0)*72 + lane]);
      float tl = bf2f(sh.c[w][(rb + 15)*72 + lane]);
      float a = (1.0f - alpha) * g0 + alpha * g2;
      float x = g1 - a;
      int I = I0 + ih;
      Ab[(size_t)I*256 + w*64 + lane] = f2bf(a);
      float xx = x*x, aa = a*a, sc = hd*tl;
      #pragma unroll
      for (int mk = 1; mk < 64; mk <<= 1) {
        xx += __shfl_xor(xx, mk, 64);
        aa += __shfl_xor(aa, mk, 64);
        sc += __shfl_xor(sc, mk, 64);
      }
      if (lane == 0) { s_bb[w][ih][0] = xx; s_bb[w][ih][1] = aa; s_bb[w][ih][2] = sc; }
    }
    __syncthreads();
    if (tid < 2) {
      int I = I0 + tid;
      float XX = s_bb[0][tid][0] + s_bb[1][tid][0] + s_bb[2][tid][0] + s_bb[3][tid][0];
      float AA = s_bb[0][tid][1] + s_bb[1][tid][1] + s_bb[2][tid][1] + s_bb[3][tid][1];
      float SC = s_bb[0][tid][2] + s_bb[1][tid][2] + s_bb[2][tid][2] + s_bb[3][tid][2];
      int bh = s_brg[tid][0], bp = s_brg[tid][1], bt = s_brg[tid][2];
      float alpha = ((float)bp - (float)bh) / ((float)bt - (float)bh);
      float sigma = alpha * ((float)bt - (float)bp);
      float inv2s2 = 1.0f / (2.0f * sigma * sigma);
      prm[I*2+0] = inv2s2;
      prm[I*2+1] = AA;
      numer[I] = expf(-XX * inv2s2);
      float sp = log1pf(expf(0.3f - SC));
      atomicAdd(wsum + 1, sp * (1.0f / 1600.0f));
      int pos = atomicAdd(cnt + bp, 1);
      lst[bp * 1600 + pos] = I;
    }
  }
}

// ---------------- top-5 helpers ----------------
__device__ __forceinline__ void sort5(float* c) {
  #define CE(i,j) { float hi = fmaxf(c[i], c[j]), lo = fminf(c[i], c[j]); c[i]=hi; c[j]=lo; }
  CE(0,1) CE(3,4) CE(2,4) CE(2,3) CE(1,4) CE(0,3) CE(0,2) CE(1,3) CE(1,2)
  #undef CE
}
__device__ __forceinline__ void ins5(float* t, float v) {
  float hi, lo;
  hi = fmaxf(t[0], v); lo = fminf(t[0], v); t[0] = hi; v = lo;
  hi = fmaxf(t[1], v); lo = fminf(t[1], v); t[1] = hi; v = lo;
  hi = fmaxf(t[2], v); lo = fminf(t[2], v); t[2] = hi; v = lo;
  hi = fmaxf(t[3], v); lo = fminf(t[3], v); t[3] = hi; v = lo;
  t[4] = fmaxf(t[4], v);
}

// ---------------- K3: fused dist + per-split top-5 (64 i's/block, pipelined) ----------------
// Pb is i-major (row = j*16 + t): j-rows for one t are 8KB-strided (R0-proven).
__global__ __launch_bounds__(256) void k_cross(const ushort* __restrict__ Pb,
    const ushort* __restrict__ Ab, const float* __restrict__ prm,
    const int* __restrict__ cnt, const int* __restrict__ lst,
    float* __restrict__ part) {
  int t = blockIdx.z;
  int n_t = min(cnt[t], 1600);
  int i0 = blockIdx.y * 64;
  if (i0 >= n_t) return;
  int j0 = blockIdx.x * 128;
  __shared__ int s_gis[64];
  __shared__ float s_red[4][64][6];
  int tid = threadIdx.x;
  if (tid < 64) {
    int gi = lst[t*1600 + min(i0 + tid, n_t - 1)];
    s_gis[tid] = min(max(gi, 0), NROW - 1);
  }
  __syncthreads();
  const int w = tid >> 6, lane = tid & 63, q = lane >> 4, m = lane & 15;
  const ushort* jp0 = Pb + ((size_t)(j0 + w*32 + m)*16 + t) * 256 + q*8;
  const ushort* jp1 = jp0 + (size_t)16*16*256;
  int gi[4];
  const ushort* ip[4];
  #pragma unroll
  for (int it = 0; it < 4; it++) {
    gi[it] = s_gis[it*16 + m];
    ip[it] = Ab + (size_t)gi[it] * 256 + q*8;
  }
  f32x4 acc[2][4];   // [jt][it]
  #pragma unroll
  for (int jt = 0; jt < 2; jt++)
    #pragma unroll
    for (int it = 0; it < 4; it++) { f32x4 z = {0.f,0.f,0.f,0.f}; acc[jt][it] = z; }
  // pipelined: prefetch k+1 while MFMA-ing k
  bf16x8 jc0 = *(const bf16x8*)(jp0);
  bf16x8 jc1 = *(const bf16x8*)(jp1);
  bf16x8 ic[4];
  #pragma unroll
  for (int it = 0; it < 4; it++) ic[it] = *(const bf16x8*)(ip[it]);
  #pragma unroll
  for (int k = 0; k < 8; k++) {
    bf16x8 jn0, jn1, in[4];
    if (k < 7) {
      int o = (k + 1) * 32;
      jn0 = *(const bf16x8*)(jp0 + o);
      jn1 = *(const bf16x8*)(jp1 + o);
      #pragma unroll
      for (int it = 0; it < 4; it++) in[it] = *(const bf16x8*)(ip[it] + o);
    }
    __builtin_amdgcn_s_setprio(1);
    #pragma unroll
    for (int it = 0; it < 4; it++) {
      acc[0][it] = __builtin_amdgcn_mfma_f32_16x16x32_bf16(jc0, ic[it], acc[0][it], 0, 0, 0);
      acc[1][it] = __builtin_amdgcn_mfma_f32_16x16x32_bf16(jc1, ic[it], acc[1][it], 0, 0, 0);
    }
    __builtin_amdgcn_s_setprio(0);
    if (k < 7) { jc0 = jn0; jc1 = jn1;
      #pragma unroll
      for (int it = 0; it < 4; it++) ic[it] = in[it];
    }
  }
  // per-lane top5/self per it-column. D: row(j) = 4q+reg (+jt*16), col(i) = m.
  float top[4][5], selfv[4];
  float pi[4], pa[4];
  #pragma unroll
  for (int it = 0; it < 4; it++) {
    pi[it] = prm[gi[it]*2]; pa[it] = prm[gi[it]*2+1];
    selfv[it] = -1e30f;
    #pragma unroll
    for (int k = 0; k < 5; k++) top[it][k] = -1e30f;
  }
  #pragma unroll
  for (int jt = 0; jt < 2; jt++)
    #pragma unroll
    for (int reg = 0; reg < 4; reg++) {
      int j = j0 + w*32 + jt*16 + 4*q + reg;
      #pragma unroll
      for (int it = 0; it < 4; it++) {
        float d = -(1.0f - 2.0f*acc[jt][it][reg] + pa[it]) * pi[it];
        if (j == gi[it]) selfv[it] = d; else ins5(top[it], d);
      }
    }
  // reduce over q (lane bits 4,5): bitonic 5-merge + self max
  #pragma unroll
  for (int mk = 16; mk <= 32; mk <<= 1) {
    #pragma unroll
    for (int it = 0; it < 4; it++) {
      float o[5], c[5];
      #pragma unroll
      for (int k = 0; k < 5; k++) o[k] = __shfl_xor(top[it][k], mk, 64);
      #pragma unroll
      for (int k = 0; k < 5; k++) c[k] = fmaxf(top[it][k], o[4 - k]);
      sort5(c);
      #pragma unroll
      for (int k = 0; k < 5; k++) top[it][k] = c[k];
      selfv[it] = fmaxf(selfv[it], __shfl_xor(selfv[it], mk, 64));
    }
  }
  if (q == 0) {
    #pragma unroll
    for (int it = 0; it < 4; it++) {
      #pragma unroll
      for (int k = 0; k < 5; k++) s_red[w][it*16 + m][k] = top[it][k];
      s_red[w][it*16 + m][5] = selfv[it];
    }
  }
  __syncthreads();
  if (tid < 64 && i0 + tid < n_t) {
    float T[5], S = s_red[0][tid][5];
    #pragma unroll
    for (int k = 0; k < 5; k++) T[k] = s_red[0][tid][k];
    #pragma unroll
    for (int w2 = 1; w2 < 4; w2++) {
      #pragma unroll
      for (int k = 0; k < 5; k++) ins5(T, s_red[w2][tid][k]);
      S = fmaxf(S, s_red[w2][tid][5]);
    }
    float* pp = part + ((size_t)s_gis[tid]*NSPLIT + blockIdx.x) * 6;
    #pragma unroll
    for (int k = 0; k < 5; k++) pp[k] = T[k];
    pp[5] = S;
  }
}

// ---------------- K4: parallel merge + last-block output write ----------------
__global__ __launch_bounds__(64) void k_merge(const float* __restrict__ part,
    const float* __restrict__ numer, float* __restrict__ wsum, int* __restrict__ done,
    const ushort* __restrict__ fe0, void* __restrict__ out) {
  int i = blockIdx.x * 64 + threadIdx.x;     // 25 blocks x 64 = 1600
  const float* pp = part + (size_t)i * NSPLIT * 6;
  float T[5]; float S = pp[5];
  #pragma unroll
  for (int k = 0; k < 5; k++) T[k] = pp[k];
  #pragma unroll
  for (int s = 1; s < NSPLIT; s++) {
    const float* ps = pp + s*6;
    float v0 = ps[0], v1 = ps[1], v2 = ps[2], v3 = ps[3], v4 = ps[4], v5 = ps[5];
    ins5(T, v0); ins5(T, v1); ins5(T, v2); ins5(T, v3); ins5(T, v4);
    S = fmaxf(S, v5);
  }
  float deno = expf(S);
  #pragma unroll
  for (int k = 0; k < 5; k++) deno += expf(T[k]);
  float local = numer[i] / deno;
  #pragma unroll
  for (int mk = 1; mk < 64; mk <<= 1) local += __shfl_xor(local, mk, 64);
  __shared__ int s_last;
  if (threadIdx.x == 0) {
    atomicAdd(wsum + 0, local * (1.0f / 1600.0f));
    __threadfence();
    s_last = (atomicAdd(done, 1) == 24);
  }
  __syncthreads();
  if (s_last) {
    int f = sniff_f32(fe0, threadIdx.x);
    if (threadIdx.x == 0) {
      __threadfence();
      float brown = __hip_atomic_load(wsum + 0, __ATOMIC_RELAXED, __HIP_MEMORY_SCOPE_AGENT);
      float sp    = __hip_atomic_load(wsum + 1, __ATOMIC_RELAXED, __HIP_MEMORY_SCOPE_AGENT);
      if (f) {
        ((float*)out)[0] = brown;
        ((float*)out)[1] = sp;
      } else {
        ushort* o = (ushort*)out;
        o[0] = f2bf(brown);
        o[1] = f2bf(sp);
      }
    }
  }
}

extern "C" void kernel_launch(void* const* d_in, const int* in_sizes, int n_in,
                              void* d_out, int out_size, void* d_ws, size_t ws_size,
                              hipStream_t stream) {
  const ushort* fe0    = (const ushort*)d_in[0];
  const ushort* fe1    = (const ushort*)d_in[1];
  const ushort* W      = (const ushort*)d_in[2];
  const ushort* bias   = (const ushort*)d_in[3];
  const int*    bridge = (const int*)d_in[4];

  // workspace (~28 MB)
  ushort* Pb    = (ushort*)d_ws;               // 13,107,200 ushorts (i-major)
  ushort* Ab    = Pb + 13107200;               // 409,600
  ushort* Wtf   = Ab + 409600;                 // 65,536
  float*  part  = (float*)(Wtf + 65536);       // 1600*25*6 = 240,000
  float*  prm   = part + 240000;               // 3,200
  float*  numer = prm + 3200;                  // 1,600
  float*  wsum  = numer + 1600;                // 4 floats
  int*    cnt   = (int*)(wsum + 4);            // 16
  int*    done  = cnt + 16;                    // 1
  int*    lst   = done + 1;                    // 25,600

  k_prep  <<<256, 256, 0, stream>>>(W, Wtf, (int*)wsum);
  k_proj  <<<1600, 256, 0, stream>>>(fe0, fe1, Wtf, bias, bridge, Pb, Ab, prm, numer, cnt, lst, wsum);
  k_cross <<<dim3(NSPLIT, 7, 16), 256, 0, stream>>>(Pb, Ab, prm, cnt, lst, part);
  k_merge <<<25, 64, 0, stream>>>(part, numer, wsum, done, fe0, d_out);
}